// Round 17
// baseline (314.328 us; speedup 1.0000x reference)
//
#include <hip/hip_runtime.h>
#include <hip/hip_bf16.h>

// SimpleAttention fused block on MI355X (gfx950), bf16 MFMA pipeline.
// B=2, S=2048, D_MODEL=2048, H=16, DK=128.
//
// R17: attention = per-(bh,qt) blocks (grid 512), single 32KiB K/V buffer,
//  NO kv-split/partials (R15's thrash source). 4-5 blocks/CU co-resident
//  (16-20 waves/CU vs 4 in R12-R16 = the measured TLP ceiling); barrier
//  drains hidden by co-residents (m114). Imbalance (qt+1 tiles) handled by
//  2x-oversubscribed grid + descending-qt dispatch (big first, small backfill).
//  gemm384 / gemm_o / prep unchanged.
//
// ws layout (bytes):          size
//  xb      [4096,2048] bf16    16M @ 0
//  wqkvb   [6144,2048] bf16    24M @ 16M
//  wob     [2048,2048] bf16     8M @ 40M
//  Qb  [B,H,S,128] bf16        16M @ 48M   (raw, rope applied in attn)
//  Kb  [B,H,S,128] bf16        16M @ 64M   (roped by gemm384 epilogue)
//  Vt  [B,H,128,S] bf16        16M @ 80M
//  Ao  [B,S,2048]  bf16        16M @ 96M
//  ctab [2048,64] f32         512K @ 112M
//  stab [2048,64] f32         512K @ 113M

typedef __bf16 bf16;
typedef __bf16 bf16x4 __attribute__((ext_vector_type(4)));
typedef __bf16 bf16x8 __attribute__((ext_vector_type(8)));
typedef float f32x4 __attribute__((ext_vector_type(4)));
typedef float f32x16 __attribute__((ext_vector_type(16)));
typedef int i32x4 __attribute__((ext_vector_type(4)));

#define DEV __device__ __forceinline__

DEV void gll16(const void* g, void* lds_base_wave_uniform) {
  __builtin_amdgcn_global_load_lds((const __attribute__((address_space(1))) void*)g,
                                   (__attribute__((address_space(3))) void*)lds_base_wave_uniform,
                                   16, 0, 0);
}

DEV f32x4 mfma16(bf16x8 a, bf16x8 b, f32x4 c) {
  return __builtin_amdgcn_mfma_f32_16x16x32_bf16(a, b, c, 0, 0, 0);
}
DEV f32x16 mfma32(bf16x8 a, bf16x8 b, f32x16 c) {
  return __builtin_amdgcn_mfma_f32_32x32x16_bf16(a, b, c, 0, 0, 0);
}

DEV int cvtpk(float lo, float hi) {  // {hi:bf16(hi), lo:bf16(lo)}
  int r;
  asm("v_cvt_pk_bf16_f32 %0, %1, %2" : "=v"(r) : "v"(lo), "v"(hi));
  return r;
}

// ---------------- fused prep: 3x f32->bf16 cvt + rope tables ----------------
__global__ __launch_bounds__(256) void prep_all(const float* __restrict__ x,
                                                const float* __restrict__ wqkv,
                                                const float* __restrict__ wo,
                                                bf16* __restrict__ xb,
                                                bf16* __restrict__ wqkvb,
                                                bf16* __restrict__ wob,
                                                float* __restrict__ ctab,
                                                float* __restrict__ stab) {
  const int b = blockIdx.x;
  if (b < 12288) {
    const float* in;
    bf16* out;
    int bb = b;
    if (b < 4096) {
      in = x; out = xb;
    } else if (b < 10240) {
      in = wqkv; out = wqkvb; bb -= 4096;
    } else {
      in = wo; out = wob; bb -= 10240;
    }
    const int i = (bb * 256 + threadIdx.x) << 3;
    float4 a = *(const float4*)(in + i);
    float4 c = *(const float4*)(in + i + 4);
    bf16x8 o;
    o[0] = (bf16)a.x; o[1] = (bf16)a.y; o[2] = (bf16)a.z; o[3] = (bf16)a.w;
    o[4] = (bf16)c.x; o[5] = (bf16)c.y; o[6] = (bf16)c.z; o[7] = (bf16)c.w;
    *(bf16x8*)(out + i) = o;
  } else {
    // rope tables: freq[j] = 10000^(-j/63)  (linspace(0,1,64) inclusive!)
    const int id = (b - 12288) * 256 + threadIdx.x;  // 2048*64
    const int s = id >> 6, j = id & 63;
    float freq = powf(10000.0f, -(float)j / 63.0f);
    float th = (float)s * freq;
    ctab[id] = cosf(th);
    stab[id] = sinf(th);
  }
}

// ---------------- 256x384 BK=32 triple-buffer GEMM (QKV) + fused K-rope ------
__global__ __launch_bounds__(512, 2) void gemm384(const bf16* __restrict__ A,
                                                  const bf16* __restrict__ Bt,
                                                  bf16* __restrict__ q_out,
                                                  bf16* __restrict__ k_out,
                                                  bf16* __restrict__ v_out,
                                                  const float* __restrict__ ctab,
                                                  const float* __restrict__ stab) {
  constexpr int K = 2048, NKT = 64;
  constexpr int BUFB = 40960;  // A 16384 + B 24576
  __shared__ char lds[3 * BUFB];  // 120 KiB
  const int id = blockIdx.x;
  const int swz = (id & 7) * 32 + (id >> 3);  // XCD swizzle (256 blocks)
  const int bx = swz & 15, by = swz >> 4;
  const int m0 = by << 8;      // 256-row M tile
  const int n0 = bx * 384;     // 384-col N tile
  const int tid = threadIdx.x, w = tid >> 6, l = tid & 63;
  const int wm = w >> 2, wn = w & 3;
  const int lsl = (l & 7) ^ ((l >> 3) & 7);
  const int srow = ((l >> 3) << 1) + (lsl >> 2);
  const int scol = (lsl & 3) << 3;

  auto STAGE = [&](int t, char* base) {
    const int k0 = t << 5;
#pragma unroll
    for (int c = 0; c < 2; ++c) {  // A: 256 rows = 2 issues
      const int row = (c << 7) + (w << 4) + srow;
      gll16(A + (size_t)(m0 + row) * K + k0 + scol, base + (c << 13) + (w << 10));
    }
#pragma unroll
    for (int c = 0; c < 3; ++c) {  // B: 384 rows = 3 issues
      const int row = (c << 7) + (w << 4) + srow;
      gll16(Bt + (size_t)(n0 + row) * K + k0 + scol, base + 16384 + (c << 13) + (w << 10));
    }
  };

  f32x4 acc[8][6] = {};

  STAGE(0, (char*)lds);
  STAGE(1, (char*)lds + BUFB);
  asm volatile("s_waitcnt vmcnt(5)" ::: "memory");
  __builtin_amdgcn_s_barrier();

#pragma unroll 1
  for (int t = 0, bi = 0, bj = 2; t < NKT; ++t) {
    char* rbase = (char*)lds + bi * BUFB;
    bf16x8 bfr[6];
#pragma unroll
    for (int j = 0; j < 6; ++j) {
      // permuted: head-block j>>1, half (j&1)*64, cols wn*16..+15
      const int row = ((j >> 1) << 7) + ((j & 1) << 6) + (wn << 4) + (l & 15);
      const int sr = row >> 1;
      bfr[j] = *(const bf16x8*)(rbase + 16384 + sr * 128 +
                                (((((row & 1) << 2) | (l >> 4)) ^ (sr & 7)) << 4));
    }
    bf16x8 af[4];
#pragma unroll
    for (int i = 0; i < 4; ++i) {
      const int row = (wm << 7) + (i << 4) + (l & 15);
      const int sr = row >> 1;
      af[i] = *(const bf16x8*)(rbase + sr * 128 +
                               (((((row & 1) << 2) | (l >> 4)) ^ (sr & 7)) << 4));
    }
    if (t + 2 < NKT) STAGE(t + 2, (char*)lds + bj * BUFB);
    asm volatile("s_waitcnt lgkmcnt(0)" ::: "memory");
    __builtin_amdgcn_sched_barrier(0);
    __builtin_amdgcn_s_setprio(1);
#pragma unroll
    for (int i = 0; i < 4; ++i)
#pragma unroll
      for (int j = 0; j < 6; ++j)
        acc[i][j] = mfma16(af[i], bfr[j], acc[i][j]);
    __builtin_amdgcn_s_setprio(0);
#pragma unroll
    for (int i = 0; i < 4; ++i) {  // A frag-rows 4..7
      const int row = (wm << 7) + 64 + (i << 4) + (l & 15);
      const int sr = row >> 1;
      af[i] = *(const bf16x8*)(rbase + sr * 128 +
                               (((((row & 1) << 2) | (l >> 4)) ^ (sr & 7)) << 4));
    }
    asm volatile("s_waitcnt lgkmcnt(0)" ::: "memory");
    __builtin_amdgcn_sched_barrier(0);
    __builtin_amdgcn_s_setprio(1);
#pragma unroll
    for (int i = 0; i < 4; ++i)
#pragma unroll
      for (int j = 0; j < 6; ++j)
        acc[4 + i][j] = mfma16(af[i], bfr[j], acc[4 + i][j]);
    __builtin_amdgcn_s_setprio(0);
    if (t + 2 < NKT) {
      asm volatile("s_waitcnt vmcnt(5)" ::: "memory");
    } else if (t + 2 == NKT) {
      asm volatile("s_waitcnt vmcnt(0)" ::: "memory");
    }
    __builtin_amdgcn_sched_barrier(0);
    __builtin_amdgcn_s_barrier();
    bi = (bi == 2) ? 0 : bi + 1;
    bj = (bj == 2) ? 0 : bj + 1;
  }

  // epilogue: frag (i,j): m = m0+wm*128+i*16+(l>>4)*4+r;
  // col = n0 + (j>>1)*128 + (j&1)*64 + d2, d2 = wn*16+(l&15).
  const int d2 = (wn << 4) + (l & 15);
#pragma unroll
  for (int i = 0; i < 8; ++i) {
    const int mbase = m0 + (wm << 7) + (i << 4) + ((l >> 4) << 2);
    const int b_ = mbase >> 11, sbase = mbase & 2047;
    float cc[4], ss[4];
    if (((n0 + 256) >> 11) == 1 || (n0 >> 11) == 1) {  // any K head-block in tile
#pragma unroll
      for (int r = 0; r < 4; ++r) {
        cc[r] = ctab[((sbase + r) << 6) + d2];
        ss[r] = stab[((sbase + r) << 6) + d2];
      }
    }
#pragma unroll
    for (int p = 0; p < 3; ++p) {
      const int nb = n0 + (p << 7);
      const int which = nb >> 11;
      const int h = (nb >> 7) & 15;
      if (which == 0) {  // Q raw
        const size_t base = (((size_t)((b_ << 4) | h)) * 2048 + sbase) * 128;
#pragma unroll
        for (int r = 0; r < 4; ++r) {
          q_out[base + ((size_t)r << 7) + d2]      = (bf16)acc[i][2 * p][r];
          q_out[base + ((size_t)r << 7) + d2 + 64] = (bf16)acc[i][2 * p + 1][r];
        }
      } else if (which == 1) {  // K with fused rope (from f32 acc)
        const size_t base = (((size_t)((b_ << 4) | h)) * 2048 + sbase) * 128;
#pragma unroll
        for (int r = 0; r < 4; ++r) {
          const float x1 = acc[i][2 * p][r], x2 = acc[i][2 * p + 1][r];
          k_out[base + ((size_t)r << 7) + d2]      = (bf16)(x1 * cc[r] - x2 * ss[r]);
          k_out[base + ((size_t)r << 7) + d2 + 64] = (bf16)(x1 * ss[r] + x2 * cc[r]);
        }
      } else {  // V transposed [B,H,128,S]
        bf16x4 v1, v2;
#pragma unroll
        for (int r = 0; r < 4; ++r) {
          v1[r] = (bf16)acc[i][2 * p][r];
          v2[r] = (bf16)acc[i][2 * p + 1][r];
        }
        const size_t hb = ((size_t)((b_ << 4) | h) << 18);
        *(bf16x4*)(v_out + hb + ((size_t)d2 << 11) + sbase) = v1;
        *(bf16x4*)(v_out + hb + ((size_t)(d2 + 64) << 11) + sbase) = v2;
      }
    }
  }
}

// ---------------- 128x128 BK=32 triple-buffer GEMM (out-proj), f32 out -------
template <int NTN>  // NTN = N/128 = 16
__global__ __launch_bounds__(256, 2) void gemm_o(const bf16* __restrict__ A,
                                                 const bf16* __restrict__ Bt,
                                                 float* __restrict__ f_out) {
  constexpr int K = 2048, NKT = 64;
  constexpr int BUFB = 16384;  // A 8192 + B 8192
  __shared__ char lds[3 * BUFB];  // 48 KiB
  const int nwg = 32 * NTN;  // 512
  const int id = blockIdx.x;
  const int swz = (id & 7) * (nwg >> 3) + (id >> 3);
  const int bx = swz % NTN, by = swz / NTN;
  const int m0 = by << 7, n0 = bx << 7;
  const int tid = threadIdx.x, w = tid >> 6, l = tid & 63;  // w in 0..3
  const int wm = w >> 1, wn = w & 1;
  const int lsl = (l & 7) ^ ((l >> 3) & 7);
  const int srow = ((l >> 3) << 1) + (lsl >> 2);
  const int scol = (lsl & 3) << 3;

  auto STAGE = [&](int t, char* base) {
    const int k0 = t << 5;
#pragma unroll
    for (int c = 0; c < 2; ++c) {
      const int row = (c << 6) + (w << 4) + srow;
      gll16(A + (size_t)(m0 + row) * K + k0 + scol, base + (c << 12) + (w << 10));
      gll16(Bt + (size_t)(n0 + row) * K + k0 + scol, base + 8192 + (c << 12) + (w << 10));
    }
  };

  f32x4 acc[4][4] = {};

  STAGE(0, (char*)lds);
  STAGE(1, (char*)lds + BUFB);
  asm volatile("s_waitcnt vmcnt(4)" ::: "memory");
  __builtin_amdgcn_s_barrier();

#pragma unroll 1
  for (int t = 0, bi = 0, bj = 2; t < NKT; ++t) {
    char* rbase = (char*)lds + bi * BUFB;
    bf16x8 af[4], bfr[4];
#pragma unroll
    for (int i = 0; i < 4; ++i) {
      const int row = (wm << 6) + (i << 4) + (l & 15);
      const int sr = row >> 1;
      af[i] = *(const bf16x8*)(rbase + sr * 128 +
                               (((((row & 1) << 2) | (l >> 4)) ^ (sr & 7)) << 4));
    }
#pragma unroll
    for (int j = 0; j < 4; ++j) {
      const int row = (wn << 6) + (j << 4) + (l & 15);
      const int sr = row >> 1;
      bfr[j] = *(const bf16x8*)(rbase + 8192 + sr * 128 +
                                (((((row & 1) << 2) | (l >> 4)) ^ (sr & 7)) << 4));
    }
    if (t + 2 < NKT) STAGE(t + 2, (char*)lds + bj * BUFB);
    asm volatile("s_waitcnt lgkmcnt(0)" ::: "memory");
    __builtin_amdgcn_sched_barrier(0);
    __builtin_amdgcn_s_setprio(1);
#pragma unroll
    for (int i = 0; i < 4; ++i)
#pragma unroll
      for (int j = 0; j < 4; ++j)
        acc[i][j] = mfma16(af[i], bfr[j], acc[i][j]);
    __builtin_amdgcn_s_setprio(0);
    if (t + 2 < NKT) {
      asm volatile("s_waitcnt vmcnt(4)" ::: "memory");
    } else if (t + 2 == NKT) {
      asm volatile("s_waitcnt vmcnt(0)" ::: "memory");
    }
    __builtin_amdgcn_sched_barrier(0);
    __builtin_amdgcn_s_barrier();
    bi = (bi == 2) ? 0 : bi + 1;
    bj = (bj == 2) ? 0 : bj + 1;
  }

#pragma unroll
  for (int i = 0; i < 4; ++i)
#pragma unroll
    for (int j = 0; j < 4; ++j)
#pragma unroll
      for (int r = 0; r < 4; ++r) {
        const int m = m0 + (wm << 6) + (i << 4) + ((l >> 4) << 2) + r;
        const int n = n0 + (wn << 6) + (j << 4) + (l & 15);
        f_out[(size_t)m * 2048 + n] = acc[i][j][r];
      }
}

// ---------------- causal flash attention, swapped-operand 32x32 ----------------
// R17: per-(bh,qt) block, grid 512, single 32KiB K/V buffer -> 4-5 blocks/CU
// co-resident. Descending-qt dispatch (big blocks first). Direct Ao write.
__global__ __launch_bounds__(256, 4) void attn_kernel(const bf16* __restrict__ Qb,
                                                      const bf16* __restrict__ Kb,
                                                      const bf16* __restrict__ Vt,
                                                      bf16* __restrict__ Ao,
                                                      const float* __restrict__ ctab,
                                                      const float* __restrict__ stab) {
  constexpr int S = 2048;
  __shared__ bf16 Ks[64 * 128];  // 16 KiB: [kv][d], 256B rows, swizzled
  __shared__ bf16 Vs[128 * 64];  // 16 KiB: [d][kv], 128B rows, swizzled
  const int id = blockIdx.x;  // 512
  const int xcd = id & 7, rest = id >> 3;         // rest 0..63
  const int qt = 15 - (rest & 15);                // descending qt: big first
  const int bh = (xcd << 2) | (rest >> 4);        // 4 bh per XCD (L2 locality)
  const int q0 = qt << 7;
  const int NT = (qt + 1) << 1;                   // kv64 tiles in causal range
  const int tid = threadIdx.x, w = tid >> 6, l = tid & 63;
  const int hi = l >> 5;
  const bf16* Qp = Qb + ((size_t)bh << 18);
  const bf16* Kp = Kb + ((size_t)bh << 18);
  const bf16* Vp = Vt + ((size_t)bh << 18);

  auto STAGE_KV = [&](int kv0) {
#pragma unroll
    for (int i = 0; i < 4; ++i) {
      const int rk = (w << 4) + (i << 2) + (l >> 4);  // K: 4 rows x 256B
      gll16(Kp + ((size_t)(kv0 + rk) << 7) + (((l & 15) ^ (rk & 7)) << 3),
            (char*)Ks + (w << 12) + (i << 10));
      const int rv = (w << 5) + (i << 3) + (l >> 3);  // V: 8 rows x 128B
      gll16(Vp + (size_t)rv * S + kv0 + (((l & 7) ^ (rv & 7)) << 3),
            (char*)Vs + (w << 12) + (i << 10));
    }
  };

  // Q load + in-register rope + QSCALE (pairs qf[kt]/qf[kt+4] lane-local)
  const int sq = q0 + (w << 5) + (l & 31);
  bf16x8 qf[8];
#pragma unroll
  for (int kt = 0; kt < 8; ++kt)
    qf[kt] = *(const bf16x8*)(Qp + ((size_t)sq << 7) + (kt << 4) + (hi << 3));
  {
    const float QS = 0.08838834764831845f * 1.4426950408889634f;
#pragma unroll
    for (int kt = 0; kt < 4; ++kt) {
      const int d2 = (kt << 4) + (hi << 3);
      const float* cp = ctab + (sq << 6) + d2;
      const float* sp = stab + (sq << 6) + d2;
      float4 c0 = *(const float4*)cp, c1 = *(const float4*)(cp + 4);
      float4 s0 = *(const float4*)sp, s1 = *(const float4*)(sp + 4);
      const float cA[8] = {c0.x, c0.y, c0.z, c0.w, c1.x, c1.y, c1.z, c1.w};
      const float sA[8] = {s0.x, s0.y, s0.z, s0.w, s1.x, s1.y, s1.z, s1.w};
      const bf16x8 lo = qf[kt], up = qf[kt + 4];
#pragma unroll
      for (int j2 = 0; j2 < 8; ++j2) {
        const float a = (float)lo[j2], b2 = (float)up[j2];
        qf[kt][j2]     = (bf16)((a * cA[j2] - b2 * sA[j2]) * QS);
        qf[kt + 4][j2] = (bf16)((a * sA[j2] + b2 * cA[j2]) * QS);
      }
    }
  }

  f32x16 o[4] = {};
  float mrun = -3e38f, lrun = 0.f;
  const int qminw = q0 + (w << 5);

#pragma unroll 1
  for (int t = 0; t < NT; ++t) {
    const int kv0 = t << 6;
    STAGE_KV(kv0);
    __syncthreads();  // stage drain; hidden by co-resident blocks (m114)
    if (kv0 <= qminw + 31) {
      f32x16 sc0 = {}, sc1 = {};
      __builtin_amdgcn_s_setprio(1);
#pragma unroll
      for (int kt = 0; kt < 8; ++kt) {
        const int rk0 = l & 31;
        const int coff = ((kt << 5) + (hi << 4));
        bf16x8 k0 = *(const bf16x8*)((const char*)Ks + (rk0 << 8) + (coff ^ ((rk0 & 7) << 4)));
        bf16x8 k1 = *(const bf16x8*)((const char*)Ks + ((rk0 + 32) << 8) + (coff ^ ((rk0 & 7) << 4)));
        sc0 = mfma32(k0, qf[kt], sc0);
        sc1 = mfma32(k1, qf[kt], sc1);
      }
      __builtin_amdgcn_s_setprio(0);
      if (kv0 + 63 > qminw) {  // diagonal masking
        const int qg = qminw + (l & 31);
#pragma unroll
        for (int r = 0; r < 16; ++r) {
          const int kvr = kv0 + (r & 3) + ((r >> 2) << 3) + (hi << 2);
          if (kvr > qg) sc0[r] = -3e38f;
          if (kvr + 32 > qg) sc1[r] = -3e38f;
        }
      }
      // ---- online softmax (tree reductions) ----
      f32x16 mm;
#pragma unroll
      for (int r = 0; r < 16; ++r) mm[r] = fmaxf(sc0[r], sc1[r]);
#pragma unroll
      for (int off = 8; off; off >>= 1)
#pragma unroll
        for (int r = 0; r < off; ++r) mm[r] = fmaxf(mm[r], mm[r + off]);
      float mx = mm[0];
      mx = fmaxf(mx, __shfl_xor(mx, 32));
      const float mnew = fmaxf(mrun, mx);
      if (!__all(mx <= mrun)) {  // defer-rescale
        const float alpha = exp2f(mrun - mnew);
        lrun *= alpha;
#pragma unroll
        for (int dt = 0; dt < 4; ++dt) o[dt] *= alpha;
      }
      mrun = mnew;
      float p0 = 0.f, p1 = 0.f, p2 = 0.f, p3 = 0.f;
#pragma unroll
      for (int r = 0; r < 16; r += 2) {
        sc0[r] = exp2f(sc0[r] - mnew); sc0[r + 1] = exp2f(sc0[r + 1] - mnew);
        sc1[r] = exp2f(sc1[r] - mnew); sc1[r + 1] = exp2f(sc1[r + 1] - mnew);
        p0 += sc0[r]; p1 += sc0[r + 1]; p2 += sc1[r]; p3 += sc1[r + 1];
      }
      float ps = (p0 + p1) + (p2 + p3);
      ps += __shfl_xor(ps, 32);
      lrun += ps;
      // ---- PV ----
#pragma unroll
      for (int ks = 0; ks < 4; ++ks) {
        const f32x16& s = (ks & 2) ? sc1 : sc0;
        const int rbp = (ks & 1) << 3;
        int pa_ = cvtpk(s[rbp + 0], s[rbp + 1]);
        int pb_ = cvtpk(s[rbp + 2], s[rbp + 3]);
        int pc_ = cvtpk(s[rbp + 4], s[rbp + 5]);
        int pd_ = cvtpk(s[rbp + 6], s[rbp + 7]);
        int sa = __shfl_xor(pa_, 32), sb2 = __shfl_xor(pb_, 32);
        int sc_ = __shfl_xor(pc_, 32), sd = __shfl_xor(pd_, 32);
        i32x4 pi;
        pi[0] = hi ? sc_ : pa_;
        pi[1] = hi ? sd : pb_;
        pi[2] = hi ? pc_ : sa;
        pi[3] = hi ? pd_ : sb2;
        const bf16x8 pf = __builtin_bit_cast(bf16x8, pi);
        __builtin_amdgcn_s_setprio(1);
#pragma unroll
        for (int dt = 0; dt < 4; ++dt) {
          const int rd = (dt << 5) + (l & 31);
          const bf16x8 vf = *(const bf16x8*)((const char*)Vs + (rd << 7) +
                                             (((ks << 5) + (hi << 4)) ^ ((rd & 7) << 4)));
          o[dt] = mfma32(vf, pf, o[dt]);
        }
        __builtin_amdgcn_s_setprio(0);
      }
    }
    __syncthreads();  // compute done before next stage overwrites
  }

  // ---- epilogue: lane q = l&31, d = dt*32 + (r&3) + 8*(r>>2) + 4*hi ----
  const float rinv = 1.0f / lrun;
  const int b = bh >> 4, h = bh & 15;
  bf16* Arow = Ao + (((size_t)(b * S + sq)) << 11) + (h << 7);
#pragma unroll
  for (int dt = 0; dt < 4; ++dt)
#pragma unroll
    for (int g = 0; g < 4; ++g) {
      bf16x4 ov;
#pragma unroll
      for (int r = 0; r < 4; ++r) ov[r] = (bf16)(o[dt][(g << 2) + r] * rinv);
      *(bf16x4*)(Arow + (dt << 5) + (g << 3) + (hi << 2)) = ov;
    }
}

// ---------------- launch ----------------
extern "C" void kernel_launch(void* const* d_in, const int* in_sizes, int n_in,
                              void* d_out, int out_size, void* d_ws, size_t ws_size,
                              hipStream_t stream) {
  const float* x = (const float*)d_in[0];      // [2,2048,2048]
  const float* w_qkv = (const float*)d_in[1];  // [6144,2048]
  const float* w_o = (const float*)d_in[2];    // [2048,2048]
  float* out = (float*)d_out;                  // [2,2048,2048] f32
  char* ws = (char*)d_ws;

  bf16* xb    = (bf16*)(ws);
  bf16* wqkvb = (bf16*)(ws + (16ull << 20));
  bf16* wob   = (bf16*)(ws + (40ull << 20));
  bf16* Qb    = (bf16*)(ws + (48ull << 20));
  bf16* Kb    = (bf16*)(ws + (64ull << 20));
  bf16* Vt    = (bf16*)(ws + (80ull << 20));
  bf16* Ao    = (bf16*)(ws + (96ull << 20));
  float* ctab = (float*)(ws + (112ull << 20));
  float* stab = (float*)(ws + (113ull << 20));

  prep_all<<<12800, 256, 0, stream>>>(x, w_qkv, w_o, xb, wqkvb, wob, ctab, stab);
  gemm384<<<256, 512, 0, stream>>>(xb, wqkvb, Qb, Kb, Vt, ctab, stab);
  attn_kernel<<<512, 256, 0, stream>>>(Qb, Kb, Vt, Ao, ctab, stab);
  gemm_o<16><<<512, 256, 0, stream>>>(Ao, wob, out);
}

// Round 18
// 227.391 us; speedup vs baseline: 1.3823x; 1.3823x over previous
//
#include <hip/hip_runtime.h>
#include <hip/hip_bf16.h>

// SimpleAttention fused block on MI355X (gfx950), bf16 MFMA pipeline.
// B=2, S=2048, D_MODEL=2048, H=16, DK=128.
//
// R18: attention -> 8-wave (512-thr) blocks sharing one staged K/V stream:
//  waves 0-3 compute kv 0-63 of each 128-tile, waves 4-7 kv 64-127 (same
//  q-rows, private m/l/o). 2 waves/SIMD (R12-R17 ran 1 = latency-starved).
//  Merge once per phase through the just-consumed 64KB LDS buffer (bf16 o +
//  f32 m,l); skipped waves carry (-3e38,0,0) -> exact zero weight.
//  Uniform 17-tile pair stream (q-tile p then 15-p), grid 256, XCD-chunked.
//  gemm384 / gemm_o / prep unchanged.
//
// ws layout (bytes):          size
//  xb      [4096,2048] bf16    16M @ 0
//  wqkvb   [6144,2048] bf16    24M @ 16M
//  wob     [2048,2048] bf16     8M @ 40M
//  Qb  [B,H,S,128] bf16        16M @ 48M   (raw, rope applied in attn)
//  Kb  [B,H,S,128] bf16        16M @ 64M   (roped by gemm384 epilogue)
//  Vt  [B,H,128,S] bf16        16M @ 80M
//  Ao  [B,S,2048]  bf16        16M @ 96M
//  ctab [2048,64] f32         512K @ 112M
//  stab [2048,64] f32         512K @ 113M

typedef __bf16 bf16;
typedef __bf16 bf16x4 __attribute__((ext_vector_type(4)));
typedef __bf16 bf16x8 __attribute__((ext_vector_type(8)));
typedef float f32x4 __attribute__((ext_vector_type(4)));
typedef float f32x16 __attribute__((ext_vector_type(16)));
typedef int i32x4 __attribute__((ext_vector_type(4)));

#define DEV __device__ __forceinline__

DEV void gll16(const void* g, void* lds_base_wave_uniform) {
  __builtin_amdgcn_global_load_lds((const __attribute__((address_space(1))) void*)g,
                                   (__attribute__((address_space(3))) void*)lds_base_wave_uniform,
                                   16, 0, 0);
}

DEV f32x4 mfma16(bf16x8 a, bf16x8 b, f32x4 c) {
  return __builtin_amdgcn_mfma_f32_16x16x32_bf16(a, b, c, 0, 0, 0);
}
DEV f32x16 mfma32(bf16x8 a, bf16x8 b, f32x16 c) {
  return __builtin_amdgcn_mfma_f32_32x32x16_bf16(a, b, c, 0, 0, 0);
}

DEV int cvtpk(float lo, float hi) {  // {hi:bf16(hi), lo:bf16(lo)}
  int r;
  asm("v_cvt_pk_bf16_f32 %0, %1, %2" : "=v"(r) : "v"(lo), "v"(hi));
  return r;
}

// ---------------- fused prep: 3x f32->bf16 cvt + rope tables ----------------
__global__ __launch_bounds__(256) void prep_all(const float* __restrict__ x,
                                                const float* __restrict__ wqkv,
                                                const float* __restrict__ wo,
                                                bf16* __restrict__ xb,
                                                bf16* __restrict__ wqkvb,
                                                bf16* __restrict__ wob,
                                                float* __restrict__ ctab,
                                                float* __restrict__ stab) {
  const int b = blockIdx.x;
  if (b < 12288) {
    const float* in;
    bf16* out;
    int bb = b;
    if (b < 4096) {
      in = x; out = xb;
    } else if (b < 10240) {
      in = wqkv; out = wqkvb; bb -= 4096;
    } else {
      in = wo; out = wob; bb -= 10240;
    }
    const int i = (bb * 256 + threadIdx.x) << 3;
    float4 a = *(const float4*)(in + i);
    float4 c = *(const float4*)(in + i + 4);
    bf16x8 o;
    o[0] = (bf16)a.x; o[1] = (bf16)a.y; o[2] = (bf16)a.z; o[3] = (bf16)a.w;
    o[4] = (bf16)c.x; o[5] = (bf16)c.y; o[6] = (bf16)c.z; o[7] = (bf16)c.w;
    *(bf16x8*)(out + i) = o;
  } else {
    // rope tables: freq[j] = 10000^(-j/63)  (linspace(0,1,64) inclusive!)
    const int id = (b - 12288) * 256 + threadIdx.x;  // 2048*64
    const int s = id >> 6, j = id & 63;
    float freq = powf(10000.0f, -(float)j / 63.0f);
    float th = (float)s * freq;
    ctab[id] = cosf(th);
    stab[id] = sinf(th);
  }
}

// ---------------- 256x384 BK=32 triple-buffer GEMM (QKV) + fused K-rope ------
__global__ __launch_bounds__(512, 2) void gemm384(const bf16* __restrict__ A,
                                                  const bf16* __restrict__ Bt,
                                                  bf16* __restrict__ q_out,
                                                  bf16* __restrict__ k_out,
                                                  bf16* __restrict__ v_out,
                                                  const float* __restrict__ ctab,
                                                  const float* __restrict__ stab) {
  constexpr int K = 2048, NKT = 64;
  constexpr int BUFB = 40960;  // A 16384 + B 24576
  __shared__ char lds[3 * BUFB];  // 120 KiB
  const int id = blockIdx.x;
  const int swz = (id & 7) * 32 + (id >> 3);  // XCD swizzle (256 blocks)
  const int bx = swz & 15, by = swz >> 4;
  const int m0 = by << 8;      // 256-row M tile
  const int n0 = bx * 384;     // 384-col N tile
  const int tid = threadIdx.x, w = tid >> 6, l = tid & 63;
  const int wm = w >> 2, wn = w & 3;
  const int lsl = (l & 7) ^ ((l >> 3) & 7);
  const int srow = ((l >> 3) << 1) + (lsl >> 2);
  const int scol = (lsl & 3) << 3;

  auto STAGE = [&](int t, char* base) {
    const int k0 = t << 5;
#pragma unroll
    for (int c = 0; c < 2; ++c) {  // A: 256 rows = 2 issues
      const int row = (c << 7) + (w << 4) + srow;
      gll16(A + (size_t)(m0 + row) * K + k0 + scol, base + (c << 13) + (w << 10));
    }
#pragma unroll
    for (int c = 0; c < 3; ++c) {  // B: 384 rows = 3 issues
      const int row = (c << 7) + (w << 4) + srow;
      gll16(Bt + (size_t)(n0 + row) * K + k0 + scol, base + 16384 + (c << 13) + (w << 10));
    }
  };

  f32x4 acc[8][6] = {};

  STAGE(0, (char*)lds);
  STAGE(1, (char*)lds + BUFB);
  asm volatile("s_waitcnt vmcnt(5)" ::: "memory");
  __builtin_amdgcn_s_barrier();

#pragma unroll 1
  for (int t = 0, bi = 0, bj = 2; t < NKT; ++t) {
    char* rbase = (char*)lds + bi * BUFB;
    bf16x8 bfr[6];
#pragma unroll
    for (int j = 0; j < 6; ++j) {
      // permuted: head-block j>>1, half (j&1)*64, cols wn*16..+15
      const int row = ((j >> 1) << 7) + ((j & 1) << 6) + (wn << 4) + (l & 15);
      const int sr = row >> 1;
      bfr[j] = *(const bf16x8*)(rbase + 16384 + sr * 128 +
                                (((((row & 1) << 2) | (l >> 4)) ^ (sr & 7)) << 4));
    }
    bf16x8 af[4];
#pragma unroll
    for (int i = 0; i < 4; ++i) {
      const int row = (wm << 7) + (i << 4) + (l & 15);
      const int sr = row >> 1;
      af[i] = *(const bf16x8*)(rbase + sr * 128 +
                               (((((row & 1) << 2) | (l >> 4)) ^ (sr & 7)) << 4));
    }
    if (t + 2 < NKT) STAGE(t + 2, (char*)lds + bj * BUFB);
    asm volatile("s_waitcnt lgkmcnt(0)" ::: "memory");
    __builtin_amdgcn_sched_barrier(0);
    __builtin_amdgcn_s_setprio(1);
#pragma unroll
    for (int i = 0; i < 4; ++i)
#pragma unroll
      for (int j = 0; j < 6; ++j)
        acc[i][j] = mfma16(af[i], bfr[j], acc[i][j]);
    __builtin_amdgcn_s_setprio(0);
#pragma unroll
    for (int i = 0; i < 4; ++i) {  // A frag-rows 4..7
      const int row = (wm << 7) + 64 + (i << 4) + (l & 15);
      const int sr = row >> 1;
      af[i] = *(const bf16x8*)(rbase + sr * 128 +
                               (((((row & 1) << 2) | (l >> 4)) ^ (sr & 7)) << 4));
    }
    asm volatile("s_waitcnt lgkmcnt(0)" ::: "memory");
    __builtin_amdgcn_sched_barrier(0);
    __builtin_amdgcn_s_setprio(1);
#pragma unroll
    for (int i = 0; i < 4; ++i)
#pragma unroll
      for (int j = 0; j < 6; ++j)
        acc[4 + i][j] = mfma16(af[i], bfr[j], acc[4 + i][j]);
    __builtin_amdgcn_s_setprio(0);
    if (t + 2 < NKT) {
      asm volatile("s_waitcnt vmcnt(5)" ::: "memory");
    } else if (t + 2 == NKT) {
      asm volatile("s_waitcnt vmcnt(0)" ::: "memory");
    }
    __builtin_amdgcn_sched_barrier(0);
    __builtin_amdgcn_s_barrier();
    bi = (bi == 2) ? 0 : bi + 1;
    bj = (bj == 2) ? 0 : bj + 1;
  }

  // epilogue: frag (i,j): m = m0+wm*128+i*16+(l>>4)*4+r;
  // col = n0 + (j>>1)*128 + (j&1)*64 + d2, d2 = wn*16+(l&15).
  const int d2 = (wn << 4) + (l & 15);
#pragma unroll
  for (int i = 0; i < 8; ++i) {
    const int mbase = m0 + (wm << 7) + (i << 4) + ((l >> 4) << 2);
    const int b_ = mbase >> 11, sbase = mbase & 2047;
    float cc[4], ss[4];
    if (((n0 + 256) >> 11) == 1 || (n0 >> 11) == 1) {  // any K head-block in tile
#pragma unroll
      for (int r = 0; r < 4; ++r) {
        cc[r] = ctab[((sbase + r) << 6) + d2];
        ss[r] = stab[((sbase + r) << 6) + d2];
      }
    }
#pragma unroll
    for (int p = 0; p < 3; ++p) {
      const int nb = n0 + (p << 7);
      const int which = nb >> 11;
      const int h = (nb >> 7) & 15;
      if (which == 0) {  // Q raw
        const size_t base = (((size_t)((b_ << 4) | h)) * 2048 + sbase) * 128;
#pragma unroll
        for (int r = 0; r < 4; ++r) {
          q_out[base + ((size_t)r << 7) + d2]      = (bf16)acc[i][2 * p][r];
          q_out[base + ((size_t)r << 7) + d2 + 64] = (bf16)acc[i][2 * p + 1][r];
        }
      } else if (which == 1) {  // K with fused rope (from f32 acc)
        const size_t base = (((size_t)((b_ << 4) | h)) * 2048 + sbase) * 128;
#pragma unroll
        for (int r = 0; r < 4; ++r) {
          const float x1 = acc[i][2 * p][r], x2 = acc[i][2 * p + 1][r];
          k_out[base + ((size_t)r << 7) + d2]      = (bf16)(x1 * cc[r] - x2 * ss[r]);
          k_out[base + ((size_t)r << 7) + d2 + 64] = (bf16)(x1 * ss[r] + x2 * cc[r]);
        }
      } else {  // V transposed [B,H,128,S]
        bf16x4 v1, v2;
#pragma unroll
        for (int r = 0; r < 4; ++r) {
          v1[r] = (bf16)acc[i][2 * p][r];
          v2[r] = (bf16)acc[i][2 * p + 1][r];
        }
        const size_t hb = ((size_t)((b_ << 4) | h) << 18);
        *(bf16x4*)(v_out + hb + ((size_t)d2 << 11) + sbase) = v1;
        *(bf16x4*)(v_out + hb + ((size_t)(d2 + 64) << 11) + sbase) = v2;
      }
    }
  }
}

// ---------------- 128x128 BK=32 triple-buffer GEMM (out-proj), f32 out -------
template <int NTN>  // NTN = N/128 = 16
__global__ __launch_bounds__(256, 2) void gemm_o(const bf16* __restrict__ A,
                                                 const bf16* __restrict__ Bt,
                                                 float* __restrict__ f_out) {
  constexpr int K = 2048, NKT = 64;
  constexpr int BUFB = 16384;  // A 8192 + B 8192
  __shared__ char lds[3 * BUFB];  // 48 KiB
  const int nwg = 32 * NTN;  // 512
  const int id = blockIdx.x;
  const int swz = (id & 7) * (nwg >> 3) + (id >> 3);
  const int bx = swz % NTN, by = swz / NTN;
  const int m0 = by << 7, n0 = bx << 7;
  const int tid = threadIdx.x, w = tid >> 6, l = tid & 63;  // w in 0..3
  const int wm = w >> 1, wn = w & 1;
  const int lsl = (l & 7) ^ ((l >> 3) & 7);
  const int srow = ((l >> 3) << 1) + (lsl >> 2);
  const int scol = (lsl & 3) << 3;

  auto STAGE = [&](int t, char* base) {
    const int k0 = t << 5;
#pragma unroll
    for (int c = 0; c < 2; ++c) {
      const int row = (c << 6) + (w << 4) + srow;
      gll16(A + (size_t)(m0 + row) * K + k0 + scol, base + (c << 12) + (w << 10));
      gll16(Bt + (size_t)(n0 + row) * K + k0 + scol, base + 8192 + (c << 12) + (w << 10));
    }
  };

  f32x4 acc[4][4] = {};

  STAGE(0, (char*)lds);
  STAGE(1, (char*)lds + BUFB);
  asm volatile("s_waitcnt vmcnt(4)" ::: "memory");
  __builtin_amdgcn_s_barrier();

#pragma unroll 1
  for (int t = 0, bi = 0, bj = 2; t < NKT; ++t) {
    char* rbase = (char*)lds + bi * BUFB;
    bf16x8 af[4], bfr[4];
#pragma unroll
    for (int i = 0; i < 4; ++i) {
      const int row = (wm << 6) + (i << 4) + (l & 15);
      const int sr = row >> 1;
      af[i] = *(const bf16x8*)(rbase + sr * 128 +
                               (((((row & 1) << 2) | (l >> 4)) ^ (sr & 7)) << 4));
    }
#pragma unroll
    for (int j = 0; j < 4; ++j) {
      const int row = (wn << 6) + (j << 4) + (l & 15);
      const int sr = row >> 1;
      bfr[j] = *(const bf16x8*)(rbase + 8192 + sr * 128 +
                                (((((row & 1) << 2) | (l >> 4)) ^ (sr & 7)) << 4));
    }
    if (t + 2 < NKT) STAGE(t + 2, (char*)lds + bj * BUFB);
    asm volatile("s_waitcnt lgkmcnt(0)" ::: "memory");
    __builtin_amdgcn_sched_barrier(0);
    __builtin_amdgcn_s_setprio(1);
#pragma unroll
    for (int i = 0; i < 4; ++i)
#pragma unroll
      for (int j = 0; j < 4; ++j)
        acc[i][j] = mfma16(af[i], bfr[j], acc[i][j]);
    __builtin_amdgcn_s_setprio(0);
    if (t + 2 < NKT) {
      asm volatile("s_waitcnt vmcnt(4)" ::: "memory");
    } else if (t + 2 == NKT) {
      asm volatile("s_waitcnt vmcnt(0)" ::: "memory");
    }
    __builtin_amdgcn_sched_barrier(0);
    __builtin_amdgcn_s_barrier();
    bi = (bi == 2) ? 0 : bi + 1;
    bj = (bj == 2) ? 0 : bj + 1;
  }

#pragma unroll
  for (int i = 0; i < 4; ++i)
#pragma unroll
    for (int j = 0; j < 4; ++j)
#pragma unroll
      for (int r = 0; r < 4; ++r) {
        const int m = m0 + (wm << 6) + (i << 4) + ((l >> 4) << 2) + r;
        const int n = n0 + (wn << 6) + (j << 4) + (l & 15);
        f_out[(size_t)m * 2048 + n] = acc[i][j][r];
      }
}

// ---------------- causal flash attention, 8-wave kv-halved ----------------
// grid 256 = 32bh x 8 pairs, 512 threads. Waves 0-3: q-row group wq, kv 0-63
// of each 128-tile; waves 4-7: same rows, kv 64-127. Uniform 17-tile pair
// stream (q-tile p then 15-p). Merge via just-consumed LDS buffer per phase.
__global__ __launch_bounds__(512, 2) void attn_kernel(const bf16* __restrict__ Qb,
                                                      const bf16* __restrict__ Kb,
                                                      const bf16* __restrict__ Vt,
                                                      bf16* __restrict__ Ao,
                                                      const float* __restrict__ ctab,
                                                      const float* __restrict__ stab) {
  constexpr int S = 2048;
  __shared__ char lds[2][65536];  // per buf: K [128kv][128d] 32KB + V [128d][128kv] 32KB
  const int id = blockIdx.x;
  const int swz = (id & 7) * 32 + (id >> 3);  // 256 blocks: 32 per XCD
  const int bh = swz >> 3;                    // 4 bh per XCD
  const int pp = swz & 7;
  const int ntA = pp + 1;  // 128-kv tiles for q-tile pp
  const int NT = 17;       // ntA + (16 - pp)
  const int tid = threadIdx.x, w = tid >> 6, l = tid & 63;
  const int wq = w & 3, half = w >> 2;
  const int hi = l >> 5;
  const bf16* Qp = Qb + ((size_t)bh << 18);
  const bf16* Kp = Kb + ((size_t)bh << 18);
  const bf16* Vp = Vt + ((size_t)bh << 18);

  auto KVSEQ = [&](int ti) { return ((ti < ntA) ? ti : ti - ntA) << 7; };

  auto STAGE_KV = [&](int kv0, int bufi) {
    char* Kbase = lds[bufi];
    char* Vbase = lds[bufi] + 32768;
#pragma unroll
    for (int i = 0; i < 2; ++i) {
      const int rk = (w << 4) + (i << 3) + ((l >> 4) << 1) + (i == 0 ? 0 : 0);  // placeholder
      (void)rk;
    }
    // 8 waves x 2 iters x 4 rows... use 2 iters of 8 rows? Simpler: 2 iters, rows w*16 + i*8 + (l>>4)*2 + ...
    // Revert to explicit: 2 iterations, each wave covers 16 rows total.
#pragma unroll
    for (int i = 0; i < 2; ++i) {
      // rows: w*16 + i*8 + (l>>3); 8 lanes per row x 16B = 128B? No: 256B rows need 16 lanes.
      // Use 4 iters of 4 rows (as R16, halved per wave):
    }
#pragma unroll
    for (int i = 0; i < 2; ++i) {
      const int r0 = (w << 4) + (i << 3) + (l >> 4);      // rows w*16 + i*8 + 0..3
      const int r1 = r0 + 4;
      gll16(Kp + ((size_t)(kv0 + r0) << 7) + (((l & 15) ^ (r0 & 7)) << 3),
            Kbase + (w << 12) + (i << 11));
      gll16(Kp + ((size_t)(kv0 + r1) << 7) + (((l & 15) ^ (r1 & 7)) << 3),
            Kbase + (w << 12) + (i << 11) + 1024);
      gll16(Vp + (size_t)r0 * S + kv0 + (((l & 15) ^ (r0 & 7)) << 3),
            Vbase + (w << 12) + (i << 11));
      gll16(Vp + (size_t)r1 * S + kv0 + (((l & 15) ^ (r1 & 7)) << 3),
            Vbase + (w << 12) + (i << 11) + 1024);
    }
  };

  bf16x8 qf[8];
  auto LOAD_Q = [&](int q0_) {  // all waves: rows q0_+wq*32; in-register rope+QSCALE
    const int sq = q0_ + (wq << 5) + (l & 31);
#pragma unroll
    for (int kt = 0; kt < 8; ++kt)
      qf[kt] = *(const bf16x8*)(Qp + ((size_t)sq << 7) + (kt << 4) + (hi << 3));
    const float QS = 0.08838834764831845f * 1.4426950408889634f;
#pragma unroll
    for (int kt = 0; kt < 4; ++kt) {
      const int d2 = (kt << 4) + (hi << 3);
      const float* cp = ctab + (sq << 6) + d2;
      const float* sp = stab + (sq << 6) + d2;
      float4 c0 = *(const float4*)cp, c1 = *(const float4*)(cp + 4);
      float4 s0 = *(const float4*)sp, s1 = *(const float4*)(sp + 4);
      const float cA[8] = {c0.x, c0.y, c0.z, c0.w, c1.x, c1.y, c1.z, c1.w};
      const float sA[8] = {s0.x, s0.y, s0.z, s0.w, s1.x, s1.y, s1.z, s1.w};
      const bf16x8 lo = qf[kt], up = qf[kt + 4];
#pragma unroll
      for (int j2 = 0; j2 < 8; ++j2) {
        const float a = (float)lo[j2], b2 = (float)up[j2];
        qf[kt][j2]     = (bf16)((a * cA[j2] - b2 * sA[j2]) * QS);
        qf[kt + 4][j2] = (bf16)((a * sA[j2] + b2 * cA[j2]) * QS);
      }
    }
  };

  f32x16 o[4] = {};
  float mrun = -3e38f, lrun = 0.f;
  int q0 = pp << 7;

  // merge halves through scratch (just-consumed buffer) + write Ao (lo waves)
  auto MERGE_EPI = [&](int q0_, char* scratch) {
    bf16* ob = (bf16*)scratch;                   // [pair wq][lane][72] bf16 (36864B)
    float* ml = (float*)(scratch + 36864);       // m [4][32], l [4][32] (1KB)
    __syncthreads();  // all compute on scratch buffer done
    if (half == 1) {
      bf16* dst = ob + ((wq << 6) + l) * 72;
#pragma unroll
      for (int dt = 0; dt < 4; ++dt) {
        bf16x8 t0, t1;
#pragma unroll
        for (int e = 0; e < 8; ++e) { t0[e] = (bf16)o[dt][e]; t1[e] = (bf16)o[dt][8 + e]; }
        *(bf16x8*)(dst + (dt << 4)) = t0;
        *(bf16x8*)(dst + (dt << 4) + 8) = t1;
      }
      if (l < 32) {
        ml[(wq << 5) + l] = mrun;
        ml[128 + (wq << 5) + l] = lrun;
      }
    }
    __syncthreads();
    if (half == 0) {
      const float mhi = ml[(wq << 5) + (l & 31)];
      const float lhi = ml[128 + (wq << 5) + (l & 31)];
      const float ms = fmaxf(mrun, mhi);
      const float alo = exp2f(mrun - ms), ahi = exp2f(mhi - ms);
      const float rinv = 1.0f / (lrun * alo + lhi * ahi);
      const bf16* src = ob + ((wq << 6) + l) * 72;
      const int b = bh >> 4, h = bh & 15;
      const int sq = q0_ + (wq << 5) + (l & 31);
      bf16* Arow = Ao + (((size_t)(b * S + sq)) << 11) + (h << 7);
#pragma unroll
      for (int dt = 0; dt < 4; ++dt) {
        bf16x8 h0 = *(const bf16x8*)(src + (dt << 4));
        bf16x8 h1 = *(const bf16x8*)(src + (dt << 4) + 8);
#pragma unroll
        for (int g = 0; g < 4; ++g) {
          bf16x4 ov;
#pragma unroll
          for (int r = 0; r < 4; ++r) {
            const int e = (g << 2) + r;
            const float hv = (e < 8) ? (float)h0[e] : (float)h1[e - 8];
            ov[r] = (bf16)((o[dt][e] * alo + hv * ahi) * rinv);
          }
          *(bf16x4*)(Arow + (dt << 5) + (g << 3) + (hi << 2)) = ov;
        }
      }
    }
  };

  STAGE_KV(KVSEQ(0), 0);
  LOAD_Q(q0);
  __syncthreads();

  int bufi = 0;
#pragma unroll 1
  for (int ti = 0; ti < NT; ++ti, bufi ^= 1) {
    if (ti + 1 < NT) STAGE_KV(KVSEQ(ti + 1), bufi ^ 1);
    const int kv0 = KVSEQ(ti);
    const int kvh0 = kv0 + (half << 6);       // this wave's kv 64-range
    const int qminw = q0 + (wq << 5);
    if (kvh0 <= qminw + 31) {
      const char* Kbase = lds[bufi];
      const char* Vbase = lds[bufi] + 32768;
      f32x16 sc0 = {}, sc1 = {};
      __builtin_amdgcn_s_setprio(1);
#pragma unroll
      for (int kt = 0; kt < 8; ++kt) {
        const int rk0 = (l & 31) + (half << 6);
        const int coff = (kt << 5) + (hi << 4);
        bf16x8 k0 = *(const bf16x8*)(Kbase + (rk0 << 8) + (coff ^ ((rk0 & 7) << 4)));
        bf16x8 k1 = *(const bf16x8*)(Kbase + ((rk0 + 32) << 8) + (coff ^ (((rk0 + 32) & 7) << 4)));
        sc0 = mfma32(k0, qf[kt], sc0);
        sc1 = mfma32(k1, qf[kt], sc1);
      }
      __builtin_amdgcn_s_setprio(0);
      if (kvh0 + 63 > qminw) {  // diagonal masking
        const int qg = qminw + (l & 31);
#pragma unroll
        for (int r = 0; r < 16; ++r) {
          const int kvr = kvh0 + (r & 3) + ((r >> 2) << 3) + (hi << 2);
          if (kvr > qg) sc0[r] = -3e38f;
          if (kvr + 32 > qg) sc1[r] = -3e38f;
        }
      }
      // ---- online softmax (tree reductions) ----
      f32x16 mm;
#pragma unroll
      for (int r = 0; r < 16; ++r) mm[r] = fmaxf(sc0[r], sc1[r]);
#pragma unroll
      for (int off = 8; off; off >>= 1)
#pragma unroll
        for (int r = 0; r < off; ++r) mm[r] = fmaxf(mm[r], mm[r + off]);
      float mx = mm[0];
      mx = fmaxf(mx, __shfl_xor(mx, 32));
      const float mnew = fmaxf(mrun, mx);
      if (!__all(mx <= mrun)) {  // defer-rescale
        const float alpha = exp2f(mrun - mnew);
        lrun *= alpha;
#pragma unroll
        for (int dt = 0; dt < 4; ++dt) o[dt] *= alpha;
      }
      mrun = mnew;
      float p0 = 0.f, p1 = 0.f, p2 = 0.f, p3 = 0.f;
#pragma unroll
      for (int r = 0; r < 16; r += 2) {
        sc0[r] = exp2f(sc0[r] - mnew); sc0[r + 1] = exp2f(sc0[r + 1] - mnew);
        sc1[r] = exp2f(sc1[r] - mnew); sc1[r + 1] = exp2f(sc1[r + 1] - mnew);
        p0 += sc0[r]; p1 += sc0[r + 1]; p2 += sc1[r]; p3 += sc1[r + 1];
      }
      float ps = (p0 + p1) + (p2 + p3);
      ps += __shfl_xor(ps, 32);
      lrun += ps;
      // ---- PV (V rows = d, cols = this wave's kv half) ----
#pragma unroll
      for (int ks = 0; ks < 4; ++ks) {
        const f32x16& s = (ks & 2) ? sc1 : sc0;
        const int rbp = (ks & 1) << 3;
        int pa_ = cvtpk(s[rbp + 0], s[rbp + 1]);
        int pb_ = cvtpk(s[rbp + 2], s[rbp + 3]);
        int pc_ = cvtpk(s[rbp + 4], s[rbp + 5]);
        int pd_ = cvtpk(s[rbp + 6], s[rbp + 7]);
        int sa = __shfl_xor(pa_, 32), sb2 = __shfl_xor(pb_, 32);
        int sc_ = __shfl_xor(pc_, 32), sd = __shfl_xor(pd_, 32);
        i32x4 pi;
        pi[0] = hi ? sc_ : pa_;
        pi[1] = hi ? sd : pb_;
        pi[2] = hi ? pc_ : sa;
        pi[3] = hi ? pd_ : sb2;
        const bf16x8 pf = __builtin_bit_cast(bf16x8, pi);
        __builtin_amdgcn_s_setprio(1);
#pragma unroll
        for (int dt = 0; dt < 4; ++dt) {
          const int rd = (dt << 5) + (l & 31);
          const int coffv = (half << 7) + (ks << 5) + (hi << 4);
          const bf16x8 vf = *(const bf16x8*)(Vbase + (rd << 8) +
                                             (coffv ^ ((rd & 7) << 4)));
          o[dt] = mfma32(vf, pf, o[dt]);
        }
        __builtin_amdgcn_s_setprio(0);
      }
    }
    if (ti == ntA - 1) {  // phase seam: merge+write A, reset, switch to B
      MERGE_EPI(q0, lds[bufi]);
      q0 = (15 - pp) << 7;
#pragma unroll
      for (int dt = 0; dt < 4; ++dt)
#pragma unroll
        for (int r = 0; r < 16; ++r) o[dt][r] = 0.f;
      mrun = -3e38f; lrun = 0.f;
      LOAD_Q(q0);
    }
    __syncthreads();
  }
  MERGE_EPI(q0, lds[(NT - 1) & 1]);
}

// ---------------- launch ----------------
extern "C" void kernel_launch(void* const* d_in, const int* in_sizes, int n_in,
                              void* d_out, int out_size, void* d_ws, size_t ws_size,
                              hipStream_t stream) {
  const float* x = (const float*)d_in[0];      // [2,2048,2048]
  const float* w_qkv = (const float*)d_in[1];  // [6144,2048]
  const float* w_o = (const float*)d_in[2];    // [2048,2048]
  float* out = (float*)d_out;                  // [2,2048,2048] f32
  char* ws = (char*)d_ws;

  bf16* xb    = (bf16*)(ws);
  bf16* wqkvb = (bf16*)(ws + (16ull << 20));
  bf16* wob   = (bf16*)(ws + (40ull << 20));
  bf16* Qb    = (bf16*)(ws + (48ull << 20));
  bf16* Kb    = (bf16*)(ws + (64ull << 20));
  bf16* Vt    = (bf16*)(ws + (80ull << 20));
  bf16* Ao    = (bf16*)(ws + (96ull << 20));
  float* ctab = (float*)(ws + (112ull << 20));
  float* stab = (float*)(ws + (113ull << 20));

  prep_all<<<12800, 256, 0, stream>>>(x, w_qkv, w_o, xb, wqkvb, wob, ctab, stab);
  gemm384<<<256, 512, 0, stream>>>(xb, wqkvb, Qb, Kb, Vt, ctab, stab);
  attn_kernel<<<256, 512, 0, stream>>>(Qb, Kb, Vt, Ao, ctab, stab);
  gemm_o<16><<<512, 256, 0, stream>>>(Ao, wob, out);
}